// Round 1
// baseline (1026.297 us; speedup 1.0000x reference)
//
#include <hip/hip_runtime.h>
#include <math.h>

#define N_NODES 50000
#define N_EDGES 800000
#define FDIM    128
#define NGRAPH  128
#define CHUNK   1024
#define NCH     ((N_NODES + CHUNK - 1) / CHUNK)   // 49

// ---------------- degree count ----------------
__global__ void count_kernel(const int* __restrict__ edges, int* __restrict__ cnt) {
    int e = blockIdx.x * blockDim.x + threadIdx.x;
    if (e < N_EDGES) {
        int dst = edges[2 * e + 1];
        atomicAdd(&cnt[dst], 1);
    }
}

// ---------------- per-chunk sums for scan ----------------
__global__ void chunk_sums_kernel(const int* __restrict__ cnt, int* __restrict__ chunk_sum) {
    __shared__ int sd[256];
    int chunk = blockIdx.x, t = threadIdx.x;
    int base = chunk * CHUNK + t * 4;
    int s = 0;
    #pragma unroll
    for (int i = 0; i < 4; ++i) {
        int idx = base + i;
        if (idx < N_NODES) s += cnt[idx];
    }
    sd[t] = s;
    __syncthreads();
    for (int off = 128; off > 0; off >>= 1) {
        if (t < off) sd[t] += sd[t + off];
        __syncthreads();
    }
    if (t == 0) chunk_sum[chunk] = sd[0];
}

// ---------------- chunk offsets (tiny serial) ----------------
__global__ void chunk_offsets_kernel(const int* __restrict__ chunk_sum,
                                     int* __restrict__ chunk_off,
                                     int* __restrict__ row_ptr) {
    if (threadIdx.x == 0 && blockIdx.x == 0) {
        int run = 0;
        for (int b = 0; b < NCH; ++b) { chunk_off[b] = run; run += chunk_sum[b]; }
        row_ptr[N_NODES] = run;   // == E
    }
}

// ---------------- per-chunk exclusive scan -> row_ptr & cursor ----------------
__global__ void scan_chunks_kernel(const int* __restrict__ cnt,
                                   const int* __restrict__ chunk_off,
                                   int* __restrict__ row_ptr,
                                   int* __restrict__ cursor) {
    __shared__ int sd[256];
    int chunk = blockIdx.x, t = threadIdx.x;
    int base = chunk * CHUNK + t * 4;
    int v[4]; int s = 0;
    #pragma unroll
    for (int i = 0; i < 4; ++i) {
        int idx = base + i;
        v[i] = (idx < N_NODES) ? cnt[idx] : 0;
        s += v[i];
    }
    sd[t] = s;
    // Hillis-Steele inclusive scan over the 256 thread sums
    for (int off = 1; off < 256; off <<= 1) {
        __syncthreads();
        int tmp = (t >= off) ? sd[t - off] : 0;
        __syncthreads();
        if (t >= off) sd[t] += tmp;
    }
    __syncthreads();
    int run = sd[t] - s + chunk_off[chunk];   // exclusive prefix for this thread
    #pragma unroll
    for (int i = 0; i < 4; ++i) {
        int idx = base + i;
        if (idx < N_NODES) { row_ptr[idx] = run; cursor[idx] = run; }
        run += v[i];
    }
}

// ---------------- bucket-scatter edges by dst ----------------
__global__ void fill_csr_kernel(const int* __restrict__ edges,
                                int* __restrict__ cursor,
                                int* __restrict__ csr_src) {
    int e = blockIdx.x * blockDim.x + threadIdx.x;
    if (e < N_EDGES) {
        int2 ed = ((const int2*)edges)[e];   // x=src, y=dst
        int pos = atomicAdd(&cursor[ed.y], 1);
        csr_src[pos] = ed.x;
    }
}

// ---------------- 1/clip(deg,1) ----------------
__global__ void invdeg_kernel(const int* __restrict__ cnt, float* __restrict__ invdeg) {
    int i = blockIdx.x * blockDim.x + threadIdx.x;
    if (i < N_NODES) invdeg[i] = 1.0f / (float)max(cnt[i], 1);
}

// ---------------- CSR gather aggregation: agg[i] = (sum_{e in-edges} h[src]) / deg ----------------
__global__ void agg_kernel(const float* __restrict__ h,
                           const int* __restrict__ row_ptr,
                           const int* __restrict__ csr_src,
                           const float* __restrict__ invdeg,
                           float* __restrict__ agg) {
    int node = blockIdx.x;
    int f = threadIdx.x;   // 128
    int beg = row_ptr[node], end = row_ptr[node + 1];
    float acc = 0.0f;
    for (int e = beg; e < end; ++e) {
        int s = csr_src[e];
        acc += h[(size_t)s * FDIM + f];
    }
    agg[(size_t)node * FDIM + f] = acc * invdeg[node];
}

// ---------------- fused SAGE GEMM: out = relu(A0@W0 + A1@W1 + b) ----------------
// M x 128, K=128 each. Block: 64 rows x 128 cols, 256 threads, 8x4 micro-tile.
__global__ __launch_bounds__(256) void sage_gemm_kernel(
        const float* __restrict__ A0, const float* __restrict__ A1,
        const float* __restrict__ W0, const float* __restrict__ W1,
        const float* __restrict__ bias, float* __restrict__ out, int M) {
    __shared__ __align__(16) float As[16][68];   // [k][m], padded (68) for bank spread
    __shared__ float4 Ws[16][32];                // [k][n4]
    int t = threadIdx.x;
    int rg = t >> 5;        // 0..7 : rows rg*8 .. rg*8+7
    int cg = t & 31;        // 0..31: cols cg*4 .. cg*4+3
    int row0 = blockIdx.x * 64;

    float acc[8][4];
    #pragma unroll
    for (int i = 0; i < 8; ++i)
        #pragma unroll
        for (int j = 0; j < 4; ++j) acc[i][j] = 0.0f;

    #pragma unroll
    for (int ph = 0; ph < 2; ++ph) {
        const float* A = ph ? A1 : A0;
        const float* W = ph ? W1 : W0;
        for (int k0 = 0; k0 < 128; k0 += 16) {
            // stage A tile 64x16 (transposed into As[k][m])
            {
                int row = t >> 2;
                int c4 = (t & 3) * 4;
                int grow = row0 + row;
                float4 v = make_float4(0.f, 0.f, 0.f, 0.f);
                if (grow < M) v = *(const float4*)&A[(size_t)grow * 128 + k0 + c4];
                As[c4 + 0][row] = v.x;
                As[c4 + 1][row] = v.y;
                As[c4 + 2][row] = v.z;
                As[c4 + 3][row] = v.w;
            }
            // stage W tile 16x128 (512 float4, 2 per thread)
            {
                int i0 = t, i1 = t + 256;
                int r0 = i0 >> 5, c0 = i0 & 31;
                int r1 = i1 >> 5, c1 = i1 & 31;
                Ws[r0][c0] = *(const float4*)&W[(size_t)(k0 + r0) * 128 + c0 * 4];
                Ws[r1][c1] = *(const float4*)&W[(size_t)(k0 + r1) * 128 + c1 * 4];
            }
            __syncthreads();
            #pragma unroll
            for (int k = 0; k < 16; ++k) {
                float4 a01 = *(const float4*)&As[k][rg * 8];
                float4 a23 = *(const float4*)&As[k][rg * 8 + 4];
                float4 w = Ws[k][cg];
                float a[8] = {a01.x, a01.y, a01.z, a01.w, a23.x, a23.y, a23.z, a23.w};
                #pragma unroll
                for (int i = 0; i < 8; ++i) {
                    acc[i][0] = fmaf(a[i], w.x, acc[i][0]);
                    acc[i][1] = fmaf(a[i], w.y, acc[i][1]);
                    acc[i][2] = fmaf(a[i], w.z, acc[i][2]);
                    acc[i][3] = fmaf(a[i], w.w, acc[i][3]);
                }
            }
            __syncthreads();
        }
    }
    float4 bv = *(const float4*)&bias[cg * 4];
    #pragma unroll
    for (int i = 0; i < 8; ++i) {
        int grow = row0 + rg * 8 + i;
        if (grow < M) {
            float4 o;
            o.x = fmaxf(acc[i][0] + bv.x, 0.f);
            o.y = fmaxf(acc[i][1] + bv.y, 0.f);
            o.z = fmaxf(acc[i][2] + bv.z, 0.f);
            o.w = fmaxf(acc[i][3] + bv.w, 0.f);
            *(float4*)&out[(size_t)grow * 128 + cg * 4] = o;
        }
    }
}

// ---------------- graph mean-pool (batch sorted -> binary search bounds) ----------------
__global__ void pool_kernel(const float* __restrict__ h,
                            const int* __restrict__ batch,
                            float* __restrict__ g) {
    int gg = blockIdx.x;
    int f = threadIdx.x;   // 128
    __shared__ int sbeg, send;
    if (f == 0) {
        int lo = 0, hi = N_NODES;
        while (lo < hi) { int mid = (lo + hi) >> 1; if (batch[mid] < gg) lo = mid + 1; else hi = mid; }
        sbeg = lo;
        hi = N_NODES;
        while (lo < hi) { int mid = (lo + hi) >> 1; if (batch[mid] < gg + 1) lo = mid + 1; else hi = mid; }
        send = lo;
    }
    __syncthreads();
    float acc = 0.0f;
    for (int i = sbeg; i < send; ++i) acc += h[(size_t)i * FDIM + f];
    int c = send - sbeg;
    g[gg * FDIM + f] = acc / (float)max(c, 1);
}

// ---------------- final MLP head: sigmoid(relu(g@Wf1+bf1)@Wf2+bf2) ----------------
__global__ void mlp_kernel(const float* __restrict__ g,
                           const float* __restrict__ Wf1, const float* __restrict__ bf1,
                           const float* __restrict__ Wf2, const float* __restrict__ bf2,
                           float* __restrict__ out) {
    int gg = blockIdx.x;
    int j = threadIdx.x;   // 128
    __shared__ float row[128];
    __shared__ float red[128];
    row[j] = g[gg * 128 + j];
    __syncthreads();
    float acc = bf1[j];
    for (int k = 0; k < 128; ++k) acc = fmaf(row[k], Wf1[k * 128 + j], acc);
    float v = fmaxf(acc, 0.0f);
    red[j] = v * Wf2[j];
    __syncthreads();
    for (int off = 64; off > 0; off >>= 1) {
        if (j < off) red[j] += red[j + off];
        __syncthreads();
    }
    if (j == 0) out[gg] = 1.0f / (1.0f + expf(-(red[0] + bf2[0])));
}

extern "C" void kernel_launch(void* const* d_in, const int* in_sizes, int n_in,
                              void* d_out, int out_size, void* d_ws, size_t ws_size,
                              hipStream_t stream) {
    const float* x      = (const float*)d_in[0];
    const int*   edges  = (const int*)d_in[1];
    const int*   batch  = (const int*)d_in[2];
    const float* Wl[5]  = {(const float*)d_in[3], (const float*)d_in[6], (const float*)d_in[9],
                           (const float*)d_in[12], (const float*)d_in[15]};
    const float* Wr[5]  = {(const float*)d_in[4], (const float*)d_in[7], (const float*)d_in[10],
                           (const float*)d_in[13], (const float*)d_in[16]};
    const float* bs[5]  = {(const float*)d_in[5], (const float*)d_in[8], (const float*)d_in[11],
                           (const float*)d_in[14], (const float*)d_in[17]};
    const float* Wf1 = (const float*)d_in[18];
    const float* bf1 = (const float*)d_in[19];
    const float* Wf2 = (const float*)d_in[20];
    const float* bf2 = (const float*)d_in[21];
    float* out = (float*)d_out;

    // workspace carve-up (256B aligned)
    char* ws = (char*)d_ws;
    auto alloc = [&](size_t bytes) { void* p = (void*)ws; ws += (bytes + 255) & ~(size_t)255; return p; };
    float* hA       = (float*)alloc((size_t)N_NODES * FDIM * 4);
    float* hB       = (float*)alloc((size_t)N_NODES * FDIM * 4);
    float* agg      = (float*)alloc((size_t)N_NODES * FDIM * 4);
    int*   cnt      = (int*)alloc((size_t)N_NODES * 4);
    int*   row_ptr  = (int*)alloc((size_t)(N_NODES + 1) * 4);
    int*   cursor   = (int*)alloc((size_t)N_NODES * 4);
    int*   csr_src  = (int*)alloc((size_t)N_EDGES * 4);
    int*   chunk_sum= (int*)alloc((size_t)NCH * 4);
    int*   chunk_off= (int*)alloc((size_t)NCH * 4);
    float* invdeg   = (float*)alloc((size_t)N_NODES * 4);
    float* gbuf     = (float*)alloc((size_t)NGRAPH * FDIM * 4);
    (void)ws_size; (void)in_sizes; (void)n_in; (void)out_size;

    // ---- CSR build (once per call; ws is re-poisoned each call) ----
    hipMemsetAsync(cnt, 0, (size_t)N_NODES * 4, stream);
    count_kernel<<<(N_EDGES + 255) / 256, 256, 0, stream>>>(edges, cnt);
    chunk_sums_kernel<<<NCH, 256, 0, stream>>>(cnt, chunk_sum);
    chunk_offsets_kernel<<<1, 64, 0, stream>>>(chunk_sum, chunk_off, row_ptr);
    scan_chunks_kernel<<<NCH, 256, 0, stream>>>(cnt, chunk_off, row_ptr, cursor);
    fill_csr_kernel<<<(N_EDGES + 255) / 256, 256, 0, stream>>>(edges, cursor, csr_src);
    invdeg_kernel<<<(N_NODES + 255) / 256, 256, 0, stream>>>(cnt, invdeg);

    // ---- 5 SAGE layers ----
    const float* hcur = x;
    float* bufs[2] = {hA, hB};
    for (int l = 0; l < 5; ++l) {
        agg_kernel<<<N_NODES, 128, 0, stream>>>(hcur, row_ptr, csr_src, invdeg, agg);
        float* hnext = bufs[l & 1];
        sage_gemm_kernel<<<(N_NODES + 63) / 64, 256, 0, stream>>>(
            agg, hcur, Wl[l], Wr[l], bs[l], hnext, N_NODES);
        hcur = hnext;
    }

    // ---- pool + head ----
    pool_kernel<<<NGRAPH, 128, 0, stream>>>(hcur, batch, gbuf);
    mlp_kernel<<<NGRAPH, 128, 0, stream>>>(gbuf, Wf1, bf1, Wf2, bf2, out);
}

// Round 2
// 949.929 us; speedup vs baseline: 1.0804x; 1.0804x over previous
//
#include <hip/hip_runtime.h>
#include <math.h>

#define N_NODES 50000
#define N_EDGES 800000
#define FDIM    128
#define NGRAPH  128
#define CHUNK   1024
#define NCH     ((N_NODES + CHUNK - 1) / CHUNK)   // 49
#define POOL_NB 64                                 // nodes per pool block
#define POOL_GRID ((N_NODES + POOL_NB - 1) / POOL_NB)

// ---------------- degree count ----------------
__global__ void count_kernel(const int* __restrict__ edges, int* __restrict__ cnt) {
    int e = blockIdx.x * blockDim.x + threadIdx.x;
    if (e < N_EDGES) {
        int dst = edges[2 * e + 1];
        atomicAdd(&cnt[dst], 1);
    }
}

// ---------------- per-chunk sums for scan ----------------
__global__ void chunk_sums_kernel(const int* __restrict__ cnt, int* __restrict__ chunk_sum) {
    __shared__ int sd[256];
    int chunk = blockIdx.x, t = threadIdx.x;
    int base = chunk * CHUNK + t * 4;
    int s = 0;
    #pragma unroll
    for (int i = 0; i < 4; ++i) {
        int idx = base + i;
        if (idx < N_NODES) s += cnt[idx];
    }
    sd[t] = s;
    __syncthreads();
    for (int off = 128; off > 0; off >>= 1) {
        if (t < off) sd[t] += sd[t + off];
        __syncthreads();
    }
    if (t == 0) chunk_sum[chunk] = sd[0];
}

// ---------------- chunk offsets (tiny serial) ----------------
__global__ void chunk_offsets_kernel(const int* __restrict__ chunk_sum,
                                     int* __restrict__ chunk_off,
                                     int* __restrict__ row_ptr) {
    if (threadIdx.x == 0 && blockIdx.x == 0) {
        int run = 0;
        for (int b = 0; b < NCH; ++b) { chunk_off[b] = run; run += chunk_sum[b]; }
        row_ptr[N_NODES] = run;   // == E
    }
}

// ---------------- per-chunk exclusive scan -> row_ptr & cursor ----------------
__global__ void scan_chunks_kernel(const int* __restrict__ cnt,
                                   const int* __restrict__ chunk_off,
                                   int* __restrict__ row_ptr,
                                   int* __restrict__ cursor) {
    __shared__ int sd[256];
    int chunk = blockIdx.x, t = threadIdx.x;
    int base = chunk * CHUNK + t * 4;
    int v[4]; int s = 0;
    #pragma unroll
    for (int i = 0; i < 4; ++i) {
        int idx = base + i;
        v[i] = (idx < N_NODES) ? cnt[idx] : 0;
        s += v[i];
    }
    sd[t] = s;
    // Hillis-Steele inclusive scan over the 256 thread sums
    for (int off = 1; off < 256; off <<= 1) {
        __syncthreads();
        int tmp = (t >= off) ? sd[t - off] : 0;
        __syncthreads();
        if (t >= off) sd[t] += tmp;
    }
    __syncthreads();
    int run = sd[t] - s + chunk_off[chunk];   // exclusive prefix for this thread
    #pragma unroll
    for (int i = 0; i < 4; ++i) {
        int idx = base + i;
        if (idx < N_NODES) { row_ptr[idx] = run; cursor[idx] = run; }
        run += v[i];
    }
}

// ---------------- bucket-scatter edges by dst ----------------
__global__ void fill_csr_kernel(const int* __restrict__ edges,
                                int* __restrict__ cursor,
                                int* __restrict__ csr_src) {
    int e = blockIdx.x * blockDim.x + threadIdx.x;
    if (e < N_EDGES) {
        int2 ed = ((const int2*)edges)[e];   // x=src, y=dst
        int pos = atomicAdd(&cursor[ed.y], 1);
        csr_src[pos] = ed.x;
    }
}

// ---------------- 1/clip(deg,1) ----------------
__global__ void invdeg_kernel(const int* __restrict__ cnt, float* __restrict__ invdeg) {
    int i = blockIdx.x * blockDim.x + threadIdx.x;
    if (i < N_NODES) invdeg[i] = 1.0f / (float)max(cnt[i], 1);
}

// ---------------- CSR gather aggregation: agg[i] = (sum_{e in-edges} h[src]) / deg ----------------
__global__ void agg_kernel(const float* __restrict__ h,
                           const int* __restrict__ row_ptr,
                           const int* __restrict__ csr_src,
                           const float* __restrict__ invdeg,
                           float* __restrict__ agg) {
    int node = blockIdx.x;
    int f = threadIdx.x;   // 128
    int beg = row_ptr[node], end = row_ptr[node + 1];
    float acc = 0.0f;
    for (int e = beg; e < end; ++e) {
        int s = csr_src[e];
        acc += h[(size_t)s * FDIM + f];
    }
    agg[(size_t)node * FDIM + f] = acc * invdeg[node];
}

// ---------------- fused SAGE GEMM: out = relu(A0@W0 + A1@W1 + b) ----------------
// M x 128, K=128 each. Block: 64 rows x 128 cols, 256 threads, 8x4 micro-tile.
__global__ __launch_bounds__(256) void sage_gemm_kernel(
        const float* __restrict__ A0, const float* __restrict__ A1,
        const float* __restrict__ W0, const float* __restrict__ W1,
        const float* __restrict__ bias, float* __restrict__ out, int M) {
    __shared__ __align__(16) float As[16][68];   // [k][m], padded (68) for bank spread
    __shared__ float4 Ws[16][32];                // [k][n4]
    int t = threadIdx.x;
    int rg = t >> 5;        // 0..7 : rows rg*8 .. rg*8+7
    int cg = t & 31;        // 0..31: cols cg*4 .. cg*4+3
    int row0 = blockIdx.x * 64;

    float acc[8][4];
    #pragma unroll
    for (int i = 0; i < 8; ++i)
        #pragma unroll
        for (int j = 0; j < 4; ++j) acc[i][j] = 0.0f;

    #pragma unroll
    for (int ph = 0; ph < 2; ++ph) {
        const float* A = ph ? A1 : A0;
        const float* W = ph ? W1 : W0;
        for (int k0 = 0; k0 < 128; k0 += 16) {
            // stage A tile 64x16 (transposed into As[k][m])
            {
                int row = t >> 2;
                int c4 = (t & 3) * 4;
                int grow = row0 + row;
                float4 v = make_float4(0.f, 0.f, 0.f, 0.f);
                if (grow < M) v = *(const float4*)&A[(size_t)grow * 128 + k0 + c4];
                As[c4 + 0][row] = v.x;
                As[c4 + 1][row] = v.y;
                As[c4 + 2][row] = v.z;
                As[c4 + 3][row] = v.w;
            }
            // stage W tile 16x128 (512 float4, 2 per thread)
            {
                int i0 = t, i1 = t + 256;
                int r0 = i0 >> 5, c0 = i0 & 31;
                int r1 = i1 >> 5, c1 = i1 & 31;
                Ws[r0][c0] = *(const float4*)&W[(size_t)(k0 + r0) * 128 + c0 * 4];
                Ws[r1][c1] = *(const float4*)&W[(size_t)(k0 + r1) * 128 + c1 * 4];
            }
            __syncthreads();
            #pragma unroll
            for (int k = 0; k < 16; ++k) {
                float4 a01 = *(const float4*)&As[k][rg * 8];
                float4 a23 = *(const float4*)&As[k][rg * 8 + 4];
                float4 w = Ws[k][cg];
                float a[8] = {a01.x, a01.y, a01.z, a01.w, a23.x, a23.y, a23.z, a23.w};
                #pragma unroll
                for (int i = 0; i < 8; ++i) {
                    acc[i][0] = fmaf(a[i], w.x, acc[i][0]);
                    acc[i][1] = fmaf(a[i], w.y, acc[i][1]);
                    acc[i][2] = fmaf(a[i], w.z, acc[i][2]);
                    acc[i][3] = fmaf(a[i], w.w, acc[i][3]);
                }
            }
            __syncthreads();
        }
    }
    float4 bv = *(const float4*)&bias[cg * 4];
    #pragma unroll
    for (int i = 0; i < 8; ++i) {
        int grow = row0 + rg * 8 + i;
        if (grow < M) {
            float4 o;
            o.x = fmaxf(acc[i][0] + bv.x, 0.f);
            o.y = fmaxf(acc[i][1] + bv.y, 0.f);
            o.z = fmaxf(acc[i][2] + bv.z, 0.f);
            o.w = fmaxf(acc[i][3] + bv.w, 0.f);
            *(float4*)&out[(size_t)grow * 128 + cg * 4] = o;
        }
    }
}

// ---------------- node-parallel graph-sum pool (batch sorted) ----------------
// Each block owns POOL_NB contiguous nodes; since batch is sorted the slice
// spans ~1-2 graphs -> ~2 atomicAdd flushes per feature lane per block.
__global__ void pool_sum_kernel(const float* __restrict__ h,
                                const int* __restrict__ batch,
                                float* __restrict__ gsum) {
    int f = threadIdx.x;                 // 128 feature lanes
    int beg = blockIdx.x * POOL_NB;
    int end = min(beg + POOL_NB, N_NODES);
    int cur = batch[beg];                // broadcast read (same addr all lanes)
    float acc = 0.0f;
    for (int i = beg; i < end; ++i) {
        int b = batch[i];
        if (b != cur) {
            atomicAdd(&gsum[cur * FDIM + f], acc);
            acc = 0.0f;
            cur = b;
        }
        acc += h[(size_t)i * FDIM + f];
    }
    atomicAdd(&gsum[cur * FDIM + f], acc);
}

// ---------------- per-graph 1/count via binary search on sorted batch ----------------
__global__ void graph_invcnt_kernel(const int* __restrict__ batch,
                                    float* __restrict__ invcnt) {
    int g = blockIdx.x * blockDim.x + threadIdx.x;
    if (g < NGRAPH) {
        int lo = 0, hi = N_NODES;
        while (lo < hi) { int mid = (lo + hi) >> 1; if (batch[mid] < g) lo = mid + 1; else hi = mid; }
        int beg = lo;
        hi = N_NODES;
        while (lo < hi) { int mid = (lo + hi) >> 1; if (batch[mid] < g + 1) lo = mid + 1; else hi = mid; }
        invcnt[g] = 1.0f / (float)max(lo - beg, 1);
    }
}

// ---------------- final MLP head: sigmoid(relu((gsum/cnt)@Wf1+bf1)@Wf2+bf2) ----------------
__global__ void mlp_kernel(const float* __restrict__ gsum,
                           const float* __restrict__ invcnt,
                           const float* __restrict__ Wf1, const float* __restrict__ bf1,
                           const float* __restrict__ Wf2, const float* __restrict__ bf2,
                           float* __restrict__ out) {
    int gg = blockIdx.x;
    int j = threadIdx.x;   // 128
    __shared__ float row[128];
    __shared__ float red[128];
    row[j] = gsum[gg * 128 + j] * invcnt[gg];
    __syncthreads();
    float acc = bf1[j];
    for (int k = 0; k < 128; ++k) acc = fmaf(row[k], Wf1[k * 128 + j], acc);
    float v = fmaxf(acc, 0.0f);
    red[j] = v * Wf2[j];
    __syncthreads();
    for (int off = 64; off > 0; off >>= 1) {
        if (j < off) red[j] += red[j + off];
        __syncthreads();
    }
    if (j == 0) out[gg] = 1.0f / (1.0f + expf(-(red[0] + bf2[0])));
}

extern "C" void kernel_launch(void* const* d_in, const int* in_sizes, int n_in,
                              void* d_out, int out_size, void* d_ws, size_t ws_size,
                              hipStream_t stream) {
    const float* x      = (const float*)d_in[0];
    const int*   edges  = (const int*)d_in[1];
    const int*   batch  = (const int*)d_in[2];
    const float* Wl[5]  = {(const float*)d_in[3], (const float*)d_in[6], (const float*)d_in[9],
                           (const float*)d_in[12], (const float*)d_in[15]};
    const float* Wr[5]  = {(const float*)d_in[4], (const float*)d_in[7], (const float*)d_in[10],
                           (const float*)d_in[13], (const float*)d_in[16]};
    const float* bs[5]  = {(const float*)d_in[5], (const float*)d_in[8], (const float*)d_in[11],
                           (const float*)d_in[14], (const float*)d_in[17]};
    const float* Wf1 = (const float*)d_in[18];
    const float* bf1 = (const float*)d_in[19];
    const float* Wf2 = (const float*)d_in[20];
    const float* bf2 = (const float*)d_in[21];
    float* out = (float*)d_out;

    // workspace carve-up (256B aligned)
    char* ws = (char*)d_ws;
    auto alloc = [&](size_t bytes) { void* p = (void*)ws; ws += (bytes + 255) & ~(size_t)255; return p; };
    float* hA       = (float*)alloc((size_t)N_NODES * FDIM * 4);
    float* hB       = (float*)alloc((size_t)N_NODES * FDIM * 4);
    float* agg      = (float*)alloc((size_t)N_NODES * FDIM * 4);
    int*   cnt      = (int*)alloc((size_t)N_NODES * 4);
    int*   row_ptr  = (int*)alloc((size_t)(N_NODES + 1) * 4);
    int*   cursor   = (int*)alloc((size_t)N_NODES * 4);
    int*   csr_src  = (int*)alloc((size_t)N_EDGES * 4);
    int*   chunk_sum= (int*)alloc((size_t)NCH * 4);
    int*   chunk_off= (int*)alloc((size_t)NCH * 4);
    float* invdeg   = (float*)alloc((size_t)N_NODES * 4);
    float* gsum     = (float*)alloc((size_t)NGRAPH * FDIM * 4);
    float* invcnt   = (float*)alloc((size_t)NGRAPH * 4);
    (void)ws_size; (void)in_sizes; (void)n_in; (void)out_size;

    // ---- CSR build (once per call; ws is re-poisoned each call) ----
    hipMemsetAsync(cnt, 0, (size_t)N_NODES * 4, stream);
    hipMemsetAsync(gsum, 0, (size_t)NGRAPH * FDIM * 4, stream);
    count_kernel<<<(N_EDGES + 255) / 256, 256, 0, stream>>>(edges, cnt);
    chunk_sums_kernel<<<NCH, 256, 0, stream>>>(cnt, chunk_sum);
    chunk_offsets_kernel<<<1, 64, 0, stream>>>(chunk_sum, chunk_off, row_ptr);
    scan_chunks_kernel<<<NCH, 256, 0, stream>>>(cnt, chunk_off, row_ptr, cursor);
    fill_csr_kernel<<<(N_EDGES + 255) / 256, 256, 0, stream>>>(edges, cursor, csr_src);
    invdeg_kernel<<<(N_NODES + 255) / 256, 256, 0, stream>>>(cnt, invdeg);
    graph_invcnt_kernel<<<1, 128, 0, stream>>>(batch, invcnt);

    // ---- 5 SAGE layers ----
    const float* hcur = x;
    float* bufs[2] = {hA, hB};
    for (int l = 0; l < 5; ++l) {
        agg_kernel<<<N_NODES, 128, 0, stream>>>(hcur, row_ptr, csr_src, invdeg, agg);
        float* hnext = bufs[l & 1];
        sage_gemm_kernel<<<(N_NODES + 63) / 64, 256, 0, stream>>>(
            agg, hcur, Wl[l], Wr[l], bs[l], hnext, N_NODES);
        hcur = hnext;
    }

    // ---- pool + head ----
    pool_sum_kernel<<<POOL_GRID, 128, 0, stream>>>(hcur, batch, gsum);
    mlp_kernel<<<NGRAPH, 128, 0, stream>>>(gsum, invcnt, Wf1, bf1, Wf2, bf2, out);
}

// Round 3
// 783.081 us; speedup vs baseline: 1.3106x; 1.2131x over previous
//
#include <hip/hip_runtime.h>
#include <math.h>

#define N_NODES 50000
#define N_EDGES 800000
#define FDIM    128
#define NGRAPH  128
#define CHUNK   1024
#define NCH     ((N_NODES + CHUNK - 1) / CHUNK)   // 49
#define POOL_NB 64                                 // nodes per pool block
#define POOL_GRID ((N_NODES + POOL_NB - 1) / POOL_NB)
#define AGG_NPB 8                                  // nodes per agg block
#define AGG_GRID ((N_NODES + AGG_NPB - 1) / AGG_NPB)

// ---------------- degree count ----------------
__global__ void count_kernel(const int* __restrict__ edges, int* __restrict__ cnt) {
    int e = blockIdx.x * blockDim.x + threadIdx.x;
    if (e < N_EDGES) {
        int2 ed = ((const int2*)edges)[e];
        atomicAdd(&cnt[ed.y], 1);
    }
}

// ---------------- per-chunk sums for scan ----------------
__global__ void chunk_sums_kernel(const int* __restrict__ cnt, int* __restrict__ chunk_sum) {
    __shared__ int sd[256];
    int chunk = blockIdx.x, t = threadIdx.x;
    int base = chunk * CHUNK + t * 4;
    int s = 0;
    #pragma unroll
    for (int i = 0; i < 4; ++i) {
        int idx = base + i;
        if (idx < N_NODES) s += cnt[idx];
    }
    sd[t] = s;
    __syncthreads();
    for (int off = 128; off > 0; off >>= 1) {
        if (t < off) sd[t] += sd[t + off];
        __syncthreads();
    }
    if (t == 0) chunk_sum[chunk] = sd[0];
}

// ---------------- chunk offsets (tiny serial) ----------------
__global__ void chunk_offsets_kernel(const int* __restrict__ chunk_sum,
                                     int* __restrict__ chunk_off,
                                     int* __restrict__ row_ptr) {
    if (threadIdx.x == 0 && blockIdx.x == 0) {
        int run = 0;
        for (int b = 0; b < NCH; ++b) { chunk_off[b] = run; run += chunk_sum[b]; }
        row_ptr[N_NODES] = run;   // == E
    }
}

// ---------------- per-chunk exclusive scan -> row_ptr & cursor ----------------
__global__ void scan_chunks_kernel(const int* __restrict__ cnt,
                                   const int* __restrict__ chunk_off,
                                   int* __restrict__ row_ptr,
                                   int* __restrict__ cursor) {
    __shared__ int sd[256];
    int chunk = blockIdx.x, t = threadIdx.x;
    int base = chunk * CHUNK + t * 4;
    int v[4]; int s = 0;
    #pragma unroll
    for (int i = 0; i < 4; ++i) {
        int idx = base + i;
        v[i] = (idx < N_NODES) ? cnt[idx] : 0;
        s += v[i];
    }
    sd[t] = s;
    // Hillis-Steele inclusive scan over the 256 thread sums
    for (int off = 1; off < 256; off <<= 1) {
        __syncthreads();
        int tmp = (t >= off) ? sd[t - off] : 0;
        __syncthreads();
        if (t >= off) sd[t] += tmp;
    }
    __syncthreads();
    int run = sd[t] - s + chunk_off[chunk];   // exclusive prefix for this thread
    #pragma unroll
    for (int i = 0; i < 4; ++i) {
        int idx = base + i;
        if (idx < N_NODES) { row_ptr[idx] = run; cursor[idx] = run; }
        run += v[i];
    }
}

// ---------------- bucket-scatter edges by dst ----------------
__global__ void fill_csr_kernel(const int* __restrict__ edges,
                                int* __restrict__ cursor,
                                int* __restrict__ csr_src) {
    int e = blockIdx.x * blockDim.x + threadIdx.x;
    if (e < N_EDGES) {
        int2 ed = ((const int2*)edges)[e];   // x=src, y=dst
        int pos = atomicAdd(&cursor[ed.y], 1);
        csr_src[pos] = ed.x;
    }
}

// ---------------- 1/clip(deg,1) ----------------
__global__ void invdeg_kernel(const int* __restrict__ cnt, float* __restrict__ invdeg) {
    int i = blockIdx.x * blockDim.x + threadIdx.x;
    if (i < N_NODES) invdeg[i] = 1.0f / (float)max(cnt[i], 1);
}

// ---------------- CSR gather aggregation (MLP-heavy: 4-edge unroll, float4 lanes) ----
// 32 threads per node (float4 each), 8 nodes per 256-thread block.
// Per 4-edge group: 4 independent index loads then 4 independent 16B row loads
// -> ~64B/lane in flight vs the old 4B dependent chain (latency-bound fix).
__global__ __launch_bounds__(256) void agg_kernel(const float* __restrict__ h,
                                                  const int* __restrict__ row_ptr,
                                                  const int* __restrict__ csr_src,
                                                  const float* __restrict__ invdeg,
                                                  float* __restrict__ agg) {
    int t = threadIdx.x;
    int local = t >> 5;                 // node slot 0..7
    int c = (t & 31) * 4;               // feature col base (float4)
    int node = blockIdx.x * AGG_NPB + local;
    if (node >= N_NODES) return;
    int beg = row_ptr[node], end = row_ptr[node + 1];
    float4 acc = make_float4(0.f, 0.f, 0.f, 0.f);
    int e = beg;
    for (; e + 4 <= end; e += 4) {
        int s0 = csr_src[e + 0];
        int s1 = csr_src[e + 1];
        int s2 = csr_src[e + 2];
        int s3 = csr_src[e + 3];
        float4 v0 = *(const float4*)&h[(size_t)s0 * FDIM + c];
        float4 v1 = *(const float4*)&h[(size_t)s1 * FDIM + c];
        float4 v2 = *(const float4*)&h[(size_t)s2 * FDIM + c];
        float4 v3 = *(const float4*)&h[(size_t)s3 * FDIM + c];
        acc.x += v0.x + v1.x + v2.x + v3.x;
        acc.y += v0.y + v1.y + v2.y + v3.y;
        acc.z += v0.z + v1.z + v2.z + v3.z;
        acc.w += v0.w + v1.w + v2.w + v3.w;
    }
    for (; e < end; ++e) {
        int s = csr_src[e];
        float4 v = *(const float4*)&h[(size_t)s * FDIM + c];
        acc.x += v.x; acc.y += v.y; acc.z += v.z; acc.w += v.w;
    }
    float inv = invdeg[node];
    float4 o = make_float4(acc.x * inv, acc.y * inv, acc.z * inv, acc.w * inv);
    *(float4*)&agg[(size_t)node * FDIM + c] = o;
}

// ---------------- fused SAGE GEMM: out = relu(A0@W0 + A1@W1 + b) ----------------
// M x 128, K=128 each. Block: 64 rows x 128 cols, 256 threads, 8x4 micro-tile.
__global__ __launch_bounds__(256) void sage_gemm_kernel(
        const float* __restrict__ A0, const float* __restrict__ A1,
        const float* __restrict__ W0, const float* __restrict__ W1,
        const float* __restrict__ bias, float* __restrict__ out, int M) {
    __shared__ __align__(16) float As[16][68];   // [k][m], padded (68) for bank spread
    __shared__ float4 Ws[16][32];                // [k][n4]
    int t = threadIdx.x;
    int rg = t >> 5;        // 0..7 : rows rg*8 .. rg*8+7
    int cg = t & 31;        // 0..31: cols cg*4 .. cg*4+3
    int row0 = blockIdx.x * 64;

    float acc[8][4];
    #pragma unroll
    for (int i = 0; i < 8; ++i)
        #pragma unroll
        for (int j = 0; j < 4; ++j) acc[i][j] = 0.0f;

    #pragma unroll
    for (int ph = 0; ph < 2; ++ph) {
        const float* A = ph ? A1 : A0;
        const float* W = ph ? W1 : W0;
        for (int k0 = 0; k0 < 128; k0 += 16) {
            // stage A tile 64x16 (transposed into As[k][m])
            {
                int row = t >> 2;
                int c4 = (t & 3) * 4;
                int grow = row0 + row;
                float4 v = make_float4(0.f, 0.f, 0.f, 0.f);
                if (grow < M) v = *(const float4*)&A[(size_t)grow * 128 + k0 + c4];
                As[c4 + 0][row] = v.x;
                As[c4 + 1][row] = v.y;
                As[c4 + 2][row] = v.z;
                As[c4 + 3][row] = v.w;
            }
            // stage W tile 16x128 (512 float4, 2 per thread)
            {
                int i0 = t, i1 = t + 256;
                int r0 = i0 >> 5, c0 = i0 & 31;
                int r1 = i1 >> 5, c1 = i1 & 31;
                Ws[r0][c0] = *(const float4*)&W[(size_t)(k0 + r0) * 128 + c0 * 4];
                Ws[r1][c1] = *(const float4*)&W[(size_t)(k0 + r1) * 128 + c1 * 4];
            }
            __syncthreads();
            #pragma unroll
            for (int k = 0; k < 16; ++k) {
                float4 a01 = *(const float4*)&As[k][rg * 8];
                float4 a23 = *(const float4*)&As[k][rg * 8 + 4];
                float4 w = Ws[k][cg];
                float a[8] = {a01.x, a01.y, a01.z, a01.w, a23.x, a23.y, a23.z, a23.w};
                #pragma unroll
                for (int i = 0; i < 8; ++i) {
                    acc[i][0] = fmaf(a[i], w.x, acc[i][0]);
                    acc[i][1] = fmaf(a[i], w.y, acc[i][1]);
                    acc[i][2] = fmaf(a[i], w.z, acc[i][2]);
                    acc[i][3] = fmaf(a[i], w.w, acc[i][3]);
                }
            }
            __syncthreads();
        }
    }
    float4 bv = *(const float4*)&bias[cg * 4];
    #pragma unroll
    for (int i = 0; i < 8; ++i) {
        int grow = row0 + rg * 8 + i;
        if (grow < M) {
            float4 o;
            o.x = fmaxf(acc[i][0] + bv.x, 0.f);
            o.y = fmaxf(acc[i][1] + bv.y, 0.f);
            o.z = fmaxf(acc[i][2] + bv.z, 0.f);
            o.w = fmaxf(acc[i][3] + bv.w, 0.f);
            *(float4*)&out[(size_t)grow * 128 + cg * 4] = o;
        }
    }
}

// ---------------- node-parallel graph-sum pool (batch sorted) ----------------
__global__ void pool_sum_kernel(const float* __restrict__ h,
                                const int* __restrict__ batch,
                                float* __restrict__ gsum) {
    int f = threadIdx.x;                 // 128 feature lanes
    int beg = blockIdx.x * POOL_NB;
    int end = min(beg + POOL_NB, N_NODES);
    int cur = batch[beg];                // broadcast read (same addr all lanes)
    float acc = 0.0f;
    for (int i = beg; i < end; ++i) {
        int b = batch[i];
        if (b != cur) {
            atomicAdd(&gsum[cur * FDIM + f], acc);
            acc = 0.0f;
            cur = b;
        }
        acc += h[(size_t)i * FDIM + f];
    }
    atomicAdd(&gsum[cur * FDIM + f], acc);
}

// ---------------- per-graph 1/count via binary search on sorted batch ----------------
__global__ void graph_invcnt_kernel(const int* __restrict__ batch,
                                    float* __restrict__ invcnt) {
    int g = blockIdx.x * blockDim.x + threadIdx.x;
    if (g < NGRAPH) {
        int lo = 0, hi = N_NODES;
        while (lo < hi) { int mid = (lo + hi) >> 1; if (batch[mid] < g) lo = mid + 1; else hi = mid; }
        int beg = lo;
        hi = N_NODES;
        while (lo < hi) { int mid = (lo + hi) >> 1; if (batch[mid] < g + 1) lo = mid + 1; else hi = mid; }
        invcnt[g] = 1.0f / (float)max(lo - beg, 1);
    }
}

// ---------------- final MLP head: sigmoid(relu((gsum/cnt)@Wf1+bf1)@Wf2+bf2) ----------------
__global__ void mlp_kernel(const float* __restrict__ gsum,
                           const float* __restrict__ invcnt,
                           const float* __restrict__ Wf1, const float* __restrict__ bf1,
                           const float* __restrict__ Wf2, const float* __restrict__ bf2,
                           float* __restrict__ out) {
    int gg = blockIdx.x;
    int j = threadIdx.x;   // 128
    __shared__ float row[128];
    __shared__ float red[128];
    row[j] = gsum[gg * 128 + j] * invcnt[gg];
    __syncthreads();
    float acc = bf1[j];
    for (int k = 0; k < 128; ++k) acc = fmaf(row[k], Wf1[k * 128 + j], acc);
    float v = fmaxf(acc, 0.0f);
    red[j] = v * Wf2[j];
    __syncthreads();
    for (int off = 64; off > 0; off >>= 1) {
        if (j < off) red[j] += red[j + off];
        __syncthreads();
    }
    if (j == 0) out[gg] = 1.0f / (1.0f + expf(-(red[0] + bf2[0])));
}

extern "C" void kernel_launch(void* const* d_in, const int* in_sizes, int n_in,
                              void* d_out, int out_size, void* d_ws, size_t ws_size,
                              hipStream_t stream) {
    const float* x      = (const float*)d_in[0];
    const int*   edges  = (const int*)d_in[1];
    const int*   batch  = (const int*)d_in[2];
    const float* Wl[5]  = {(const float*)d_in[3], (const float*)d_in[6], (const float*)d_in[9],
                           (const float*)d_in[12], (const float*)d_in[15]};
    const float* Wr[5]  = {(const float*)d_in[4], (const float*)d_in[7], (const float*)d_in[10],
                           (const float*)d_in[13], (const float*)d_in[16]};
    const float* bs[5]  = {(const float*)d_in[5], (const float*)d_in[8], (const float*)d_in[11],
                           (const float*)d_in[14], (const float*)d_in[17]};
    const float* Wf1 = (const float*)d_in[18];
    const float* bf1 = (const float*)d_in[19];
    const float* Wf2 = (const float*)d_in[20];
    const float* bf2 = (const float*)d_in[21];
    float* out = (float*)d_out;

    // workspace carve-up (256B aligned)
    char* ws = (char*)d_ws;
    auto alloc = [&](size_t bytes) { void* p = (void*)ws; ws += (bytes + 255) & ~(size_t)255; return p; };
    float* hA       = (float*)alloc((size_t)N_NODES * FDIM * 4);
    float* hB       = (float*)alloc((size_t)N_NODES * FDIM * 4);
    float* agg      = (float*)alloc((size_t)N_NODES * FDIM * 4);
    int*   cnt      = (int*)alloc((size_t)N_NODES * 4);
    int*   row_ptr  = (int*)alloc((size_t)(N_NODES + 1) * 4);
    int*   cursor   = (int*)alloc((size_t)N_NODES * 4);
    int*   csr_src  = (int*)alloc((size_t)N_EDGES * 4);
    int*   chunk_sum= (int*)alloc((size_t)NCH * 4);
    int*   chunk_off= (int*)alloc((size_t)NCH * 4);
    float* invdeg   = (float*)alloc((size_t)N_NODES * 4);
    float* gsum     = (float*)alloc((size_t)NGRAPH * FDIM * 4);
    float* invcnt   = (float*)alloc((size_t)NGRAPH * 4);
    (void)ws_size; (void)in_sizes; (void)n_in; (void)out_size;

    // ---- CSR build (once per call; ws is re-poisoned each call) ----
    hipMemsetAsync(cnt, 0, (size_t)N_NODES * 4, stream);
    hipMemsetAsync(gsum, 0, (size_t)NGRAPH * FDIM * 4, stream);
    count_kernel<<<(N_EDGES + 255) / 256, 256, 0, stream>>>(edges, cnt);
    chunk_sums_kernel<<<NCH, 256, 0, stream>>>(cnt, chunk_sum);
    chunk_offsets_kernel<<<1, 64, 0, stream>>>(chunk_sum, chunk_off, row_ptr);
    scan_chunks_kernel<<<NCH, 256, 0, stream>>>(cnt, chunk_off, row_ptr, cursor);
    fill_csr_kernel<<<(N_EDGES + 255) / 256, 256, 0, stream>>>(edges, cursor, csr_src);
    invdeg_kernel<<<(N_NODES + 255) / 256, 256, 0, stream>>>(cnt, invdeg);
    graph_invcnt_kernel<<<1, 128, 0, stream>>>(batch, invcnt);

    // ---- 5 SAGE layers ----
    const float* hcur = x;
    float* bufs[2] = {hA, hB};
    for (int l = 0; l < 5; ++l) {
        agg_kernel<<<AGG_GRID, 256, 0, stream>>>(hcur, row_ptr, csr_src, invdeg, agg);
        float* hnext = bufs[l & 1];
        sage_gemm_kernel<<<(N_NODES + 63) / 64, 256, 0, stream>>>(
            agg, hcur, Wl[l], Wr[l], bs[l], hnext, N_NODES);
        hcur = hnext;
    }

    // ---- pool + head ----
    pool_sum_kernel<<<POOL_GRID, 128, 0, stream>>>(hcur, batch, gsum);
    mlp_kernel<<<NGRAPH, 128, 0, stream>>>(gsum, invcnt, Wf1, bf1, Wf2, bf2, out);
}

// Round 4
// 563.483 us; speedup vs baseline: 1.8213x; 1.3897x over previous
//
#include <hip/hip_runtime.h>
#include <math.h>

#define N_NODES 50000
#define MPAD    50048                              // 64 * 782, padded row count
#define N_EDGES 800000
#define FDIM    128
#define NGRAPH  128
#define CHUNK   1024
#define NCH     ((N_NODES + CHUNK - 1) / CHUNK)   // 49
#define POOL_NB 64
#define POOL_GRID ((N_NODES + POOL_NB - 1) / POOL_NB)

typedef __attribute__((ext_vector_type(8))) short short8;   // 8 bf16 = 4 VGPRs
typedef __attribute__((ext_vector_type(4))) float f32x4;

__device__ __forceinline__ unsigned short f2bf(float f) {   // RNE
    unsigned int u = __float_as_uint(f);
    return (unsigned short)((u + 0x7FFFu + ((u >> 16) & 1u)) >> 16);
}
__device__ __forceinline__ float bfhi(unsigned int u) { return __uint_as_float(u & 0xFFFF0000u); }
__device__ __forceinline__ float bflo(unsigned int u) { return __uint_as_float(u << 16); }

// ---------------- degree count ----------------
__global__ void count_kernel(const int* __restrict__ edges, int* __restrict__ cnt) {
    int e = blockIdx.x * blockDim.x + threadIdx.x;
    if (e < N_EDGES) {
        int2 ed = ((const int2*)edges)[e];
        atomicAdd(&cnt[ed.y], 1);
    }
}

// ---------------- per-chunk sums for scan ----------------
__global__ void chunk_sums_kernel(const int* __restrict__ cnt, int* __restrict__ chunk_sum) {
    __shared__ int sd[256];
    int chunk = blockIdx.x, t = threadIdx.x;
    int base = chunk * CHUNK + t * 4;
    int s = 0;
    #pragma unroll
    for (int i = 0; i < 4; ++i) {
        int idx = base + i;
        if (idx < N_NODES) s += cnt[idx];
    }
    sd[t] = s;
    __syncthreads();
    for (int off = 128; off > 0; off >>= 1) {
        if (t < off) sd[t] += sd[t + off];
        __syncthreads();
    }
    if (t == 0) chunk_sum[chunk] = sd[0];
}

// ---------------- chunk offsets (tiny serial) ----------------
__global__ void chunk_offsets_kernel(const int* __restrict__ chunk_sum,
                                     int* __restrict__ chunk_off,
                                     int* __restrict__ row_ptr) {
    if (threadIdx.x == 0 && blockIdx.x == 0) {
        int run = 0;
        for (int b = 0; b < NCH; ++b) { chunk_off[b] = run; run += chunk_sum[b]; }
        row_ptr[N_NODES] = run;   // == E
    }
}

// ---------------- per-chunk exclusive scan -> row_ptr & cursor ----------------
__global__ void scan_chunks_kernel(const int* __restrict__ cnt,
                                   const int* __restrict__ chunk_off,
                                   int* __restrict__ row_ptr,
                                   int* __restrict__ cursor) {
    __shared__ int sd[256];
    int chunk = blockIdx.x, t = threadIdx.x;
    int base = chunk * CHUNK + t * 4;
    int v[4]; int s = 0;
    #pragma unroll
    for (int i = 0; i < 4; ++i) {
        int idx = base + i;
        v[i] = (idx < N_NODES) ? cnt[idx] : 0;
        s += v[i];
    }
    sd[t] = s;
    for (int off = 1; off < 256; off <<= 1) {
        __syncthreads();
        int tmp = (t >= off) ? sd[t - off] : 0;
        __syncthreads();
        if (t >= off) sd[t] += tmp;
    }
    __syncthreads();
    int run = sd[t] - s + chunk_off[chunk];
    #pragma unroll
    for (int i = 0; i < 4; ++i) {
        int idx = base + i;
        if (idx < N_NODES) { row_ptr[idx] = run; cursor[idx] = run; }
        run += v[i];
    }
}

// ---------------- bucket-scatter edges by dst ----------------
__global__ void fill_csr_kernel(const int* __restrict__ edges,
                                int* __restrict__ cursor,
                                int* __restrict__ csr_src) {
    int e = blockIdx.x * blockDim.x + threadIdx.x;
    if (e < N_EDGES) {
        int2 ed = ((const int2*)edges)[e];   // x=src, y=dst
        int pos = atomicAdd(&cursor[ed.y], 1);
        csr_src[pos] = ed.x;
    }
}

// ---------------- 1/clip(deg,1) ----------------
__global__ void invdeg_kernel(const int* __restrict__ cnt, float* __restrict__ invdeg) {
    int i = blockIdx.x * blockDim.x + threadIdx.x;
    if (i < N_NODES) invdeg[i] = 1.0f / (float)max(cnt[i], 1);
}

// ---------------- x -> bf16 (padded rows zeroed) ----------------
__global__ void convert_x_kernel(const float* __restrict__ x, unsigned short* __restrict__ xb) {
    int i = blockIdx.x * blockDim.x + threadIdx.x;   // float4 group
    if (i >= MPAD * FDIM / 4) return;
    int base = i * 4;
    uint2 o;
    if (base < N_NODES * FDIM) {
        float4 v = *(const float4*)&x[base];
        o.x = (unsigned int)f2bf(v.x) | ((unsigned int)f2bf(v.y) << 16);
        o.y = (unsigned int)f2bf(v.z) | ((unsigned int)f2bf(v.w) << 16);
    } else { o.x = 0u; o.y = 0u; }
    *(uint2*)&xb[base] = o;
}

// ---------------- weights -> bf16, transposed+concatenated: Wcat[l][n][k], k in [0,256) ----
struct WPtrs { const float* wl[5]; const float* wr[5]; };
__global__ void convert_w_kernel(WPtrs wp, unsigned short* __restrict__ wcat) {
    int t = blockIdx.x * blockDim.x + threadIdx.x;   // 5*128*256
    if (t >= 5 * 128 * 256) return;
    int l = t >> 15;
    int rem = t & 32767;
    int k = rem >> 7;        // 0..255
    int n = rem & 127;       // coalesced read over n
    const float* W = (k < 128) ? wp.wl[l] : wp.wr[l];
    float v = W[(k & 127) * 128 + n];
    wcat[((size_t)l << 15) + n * 256 + k] = f2bf(v);
}

// ---------------- CSR gather aggregation, bf16 in/out, fp32 accumulate ----------------
// 16 lanes per node (16B = 8 bf16 each), 16 nodes per 256-thread block.
// 4-edge unroll: 4 independent idx loads then 4 independent 16B row loads.
__global__ __launch_bounds__(256) void agg_kernel(const unsigned short* __restrict__ h,
                                                  const int* __restrict__ row_ptr,
                                                  const int* __restrict__ csr_src,
                                                  const float* __restrict__ invdeg,
                                                  unsigned short* __restrict__ agg) {
    int t = threadIdx.x;
    int local = t >> 4;                 // node slot 0..15
    int lane = t & 15;                  // 16 feature lanes
    int node = blockIdx.x * 16 + local;
    if (node >= N_NODES) return;
    int c = lane * 8;                   // feature base (8 bf16)
    int beg = row_ptr[node], end = row_ptr[node + 1];
    float acc[8] = {0.f, 0.f, 0.f, 0.f, 0.f, 0.f, 0.f, 0.f};
    int e = beg;
    for (; e + 4 <= end; e += 4) {
        int s0 = csr_src[e + 0];
        int s1 = csr_src[e + 1];
        int s2 = csr_src[e + 2];
        int s3 = csr_src[e + 3];
        uint4 v0 = *(const uint4*)&h[(size_t)s0 * FDIM + c];
        uint4 v1 = *(const uint4*)&h[(size_t)s1 * FDIM + c];
        uint4 v2 = *(const uint4*)&h[(size_t)s2 * FDIM + c];
        uint4 v3 = *(const uint4*)&h[(size_t)s3 * FDIM + c];
        acc[0] += bflo(v0.x) + bflo(v1.x) + bflo(v2.x) + bflo(v3.x);
        acc[1] += bfhi(v0.x) + bfhi(v1.x) + bfhi(v2.x) + bfhi(v3.x);
        acc[2] += bflo(v0.y) + bflo(v1.y) + bflo(v2.y) + bflo(v3.y);
        acc[3] += bfhi(v0.y) + bfhi(v1.y) + bfhi(v2.y) + bfhi(v3.y);
        acc[4] += bflo(v0.z) + bflo(v1.z) + bflo(v2.z) + bflo(v3.z);
        acc[5] += bfhi(v0.z) + bfhi(v1.z) + bfhi(v2.z) + bfhi(v3.z);
        acc[6] += bflo(v0.w) + bflo(v1.w) + bflo(v2.w) + bflo(v3.w);
        acc[7] += bfhi(v0.w) + bfhi(v1.w) + bfhi(v2.w) + bfhi(v3.w);
    }
    for (; e < end; ++e) {
        int s = csr_src[e];
        uint4 v = *(const uint4*)&h[(size_t)s * FDIM + c];
        acc[0] += bflo(v.x); acc[1] += bfhi(v.x);
        acc[2] += bflo(v.y); acc[3] += bfhi(v.y);
        acc[4] += bflo(v.z); acc[5] += bfhi(v.z);
        acc[6] += bflo(v.w); acc[7] += bfhi(v.w);
    }
    float inv = invdeg[node];
    uint4 o;
    o.x = (unsigned int)f2bf(acc[0] * inv) | ((unsigned int)f2bf(acc[1] * inv) << 16);
    o.y = (unsigned int)f2bf(acc[2] * inv) | ((unsigned int)f2bf(acc[3] * inv) << 16);
    o.z = (unsigned int)f2bf(acc[4] * inv) | ((unsigned int)f2bf(acc[5] * inv) << 16);
    o.w = (unsigned int)f2bf(acc[6] * inv) | ((unsigned int)f2bf(acc[7] * inv) << 16);
    *(uint4*)&agg[(size_t)node * FDIM + c] = o;
}

// ---------------- fused SAGE GEMM via MFMA: out = relu([A0|A1] @ Wcat^T + b) ----------------
// Pure-register: no LDS, no barriers. Block = 4 waves, tile 64 rows x 128 cols.
// Wave: 16 rows x 8 col-blocks of 16x16x32 mfma; K = 256 (phase 0: A0/k<128, phase 1: A1).
// Layouts (verified m89/m91): A[m=lane&15][k=quad*8+j]; B[n=lane&15][k=quad*8+j];
// D: col=lane&15, row=quad*4+reg.
__global__ __launch_bounds__(256) void sage_gemm_kernel(
        const unsigned short* __restrict__ A0,   // agg bf16 [MPAD][128]
        const unsigned short* __restrict__ A1,   // h   bf16 [MPAD][128]
        const unsigned short* __restrict__ Wcat, // [128 n][256 k] bf16
        const float* __restrict__ bias,
        unsigned short* __restrict__ out) {
    int t = threadIdx.x;
    int wave = t >> 6;
    int lane = t & 63;
    int l15 = lane & 15;
    int q = lane >> 4;                   // quad 0..3
    int row_base = blockIdx.x * 64 + wave * 16;
    int arow = row_base + l15;

    f32x4 acc[8];
    #pragma unroll
    for (int i = 0; i < 8; ++i) acc[i] = (f32x4){0.f, 0.f, 0.f, 0.f};

    #pragma unroll
    for (int p = 0; p < 2; ++p) {
        const unsigned short* Ap = p ? A1 : A0;
        const unsigned short* Abase = Ap + (size_t)arow * FDIM + q * 8;
        const unsigned short* Wbase = Wcat + (size_t)l15 * 256 + p * 128 + q * 8;
        #pragma unroll
        for (int k0 = 0; k0 < 128; k0 += 32) {
            short8 a = *(const short8*)(Abase + k0);
            #pragma unroll
            for (int cb = 0; cb < 8; ++cb) {
                short8 b = *(const short8*)(Wbase + (size_t)cb * 16 * 256 + k0);
                acc[cb] = __builtin_amdgcn_mfma_f32_16x16x32_bf16(a, b, acc[cb], 0, 0, 0);
            }
        }
    }
    // epilogue: bias + relu + bf16 store (lanes 0..15 write 32 contiguous bytes per row)
    #pragma unroll
    for (int cb = 0; cb < 8; ++cb) {
        int col = cb * 16 + l15;
        float bv = bias[col];
        #pragma unroll
        for (int r = 0; r < 4; ++r) {
            int row = row_base + q * 4 + r;
            float v = fmaxf(acc[cb][r] + bv, 0.f);
            out[(size_t)row * FDIM + col] = f2bf(v);
        }
    }
}

// ---------------- node-parallel graph-sum pool (batch sorted), bf16 in ----------------
__global__ void pool_sum_kernel(const unsigned short* __restrict__ h,
                                const int* __restrict__ batch,
                                float* __restrict__ gsum) {
    int f = threadIdx.x;                 // 128 feature lanes
    int beg = blockIdx.x * POOL_NB;
    int end = min(beg + POOL_NB, N_NODES);
    int cur = batch[beg];
    float acc = 0.0f;
    for (int i = beg; i < end; ++i) {
        int b = batch[i];
        if (b != cur) {
            atomicAdd(&gsum[cur * FDIM + f], acc);
            acc = 0.0f;
            cur = b;
        }
        acc += bflo((unsigned int)h[(size_t)i * FDIM + f]);
    }
    atomicAdd(&gsum[cur * FDIM + f], acc);
}

// ---------------- per-graph 1/count via binary search on sorted batch ----------------
__global__ void graph_invcnt_kernel(const int* __restrict__ batch,
                                    float* __restrict__ invcnt) {
    int g = blockIdx.x * blockDim.x + threadIdx.x;
    if (g < NGRAPH) {
        int lo = 0, hi = N_NODES;
        while (lo < hi) { int mid = (lo + hi) >> 1; if (batch[mid] < g) lo = mid + 1; else hi = mid; }
        int beg = lo;
        hi = N_NODES;
        while (lo < hi) { int mid = (lo + hi) >> 1; if (batch[mid] < g + 1) lo = mid + 1; else hi = mid; }
        invcnt[g] = 1.0f / (float)max(lo - beg, 1);
    }
}

// ---------------- final MLP head (fp32): sigmoid(relu((gsum/cnt)@Wf1+bf1)@Wf2+bf2) -------
__global__ void mlp_kernel(const float* __restrict__ gsum,
                           const float* __restrict__ invcnt,
                           const float* __restrict__ Wf1, const float* __restrict__ bf1,
                           const float* __restrict__ Wf2, const float* __restrict__ bf2,
                           float* __restrict__ out) {
    int gg = blockIdx.x;
    int j = threadIdx.x;   // 128
    __shared__ float row[128];
    __shared__ float red[128];
    row[j] = gsum[gg * 128 + j] * invcnt[gg];
    __syncthreads();
    float acc = bf1[j];
    for (int k = 0; k < 128; ++k) acc = fmaf(row[k], Wf1[k * 128 + j], acc);
    float v = fmaxf(acc, 0.0f);
    red[j] = v * Wf2[j];
    __syncthreads();
    for (int off = 64; off > 0; off >>= 1) {
        if (j < off) red[j] += red[j + off];
        __syncthreads();
    }
    if (j == 0) out[gg] = 1.0f / (1.0f + expf(-(red[0] + bf2[0])));
}

extern "C" void kernel_launch(void* const* d_in, const int* in_sizes, int n_in,
                              void* d_out, int out_size, void* d_ws, size_t ws_size,
                              hipStream_t stream) {
    const float* x      = (const float*)d_in[0];
    const int*   edges  = (const int*)d_in[1];
    const int*   batch  = (const int*)d_in[2];
    WPtrs wp;
    const float* bs[5];
    for (int l = 0; l < 5; ++l) {
        wp.wl[l] = (const float*)d_in[3 + 3 * l];
        wp.wr[l] = (const float*)d_in[4 + 3 * l];
        bs[l]    = (const float*)d_in[5 + 3 * l];
    }
    const float* Wf1 = (const float*)d_in[18];
    const float* bf1 = (const float*)d_in[19];
    const float* Wf2 = (const float*)d_in[20];
    const float* bf2 = (const float*)d_in[21];
    float* out = (float*)d_out;

    // workspace carve-up (256B aligned)
    char* ws = (char*)d_ws;
    auto alloc = [&](size_t bytes) { void* p = (void*)ws; ws += (bytes + 255) & ~(size_t)255; return p; };
    unsigned short* xb   = (unsigned short*)alloc((size_t)MPAD * FDIM * 2);
    unsigned short* hA   = (unsigned short*)alloc((size_t)MPAD * FDIM * 2);
    unsigned short* hB   = (unsigned short*)alloc((size_t)MPAD * FDIM * 2);
    unsigned short* aggb = (unsigned short*)alloc((size_t)MPAD * FDIM * 2);
    unsigned short* wcat = (unsigned short*)alloc((size_t)5 * 128 * 256 * 2);
    int*   cnt      = (int*)alloc((size_t)N_NODES * 4);
    int*   row_ptr  = (int*)alloc((size_t)(N_NODES + 1) * 4);
    int*   cursor   = (int*)alloc((size_t)N_NODES * 4);
    int*   csr_src  = (int*)alloc((size_t)N_EDGES * 4);
    int*   chunk_sum= (int*)alloc((size_t)NCH * 4);
    int*   chunk_off= (int*)alloc((size_t)NCH * 4);
    float* invdeg   = (float*)alloc((size_t)N_NODES * 4);
    float* gsum     = (float*)alloc((size_t)NGRAPH * FDIM * 4);
    float* invcnt   = (float*)alloc((size_t)NGRAPH * 4);
    (void)ws_size; (void)in_sizes; (void)n_in; (void)out_size;

    // ---- conversions + CSR build ----
    hipMemsetAsync(cnt, 0, (size_t)N_NODES * 4, stream);
    hipMemsetAsync(gsum, 0, (size_t)NGRAPH * FDIM * 4, stream);
    convert_x_kernel<<<(MPAD * FDIM / 4 + 255) / 256, 256, 0, stream>>>(x, xb);
    convert_w_kernel<<<(5 * 128 * 256 + 255) / 256, 256, 0, stream>>>(wp, wcat);
    count_kernel<<<(N_EDGES + 255) / 256, 256, 0, stream>>>(edges, cnt);
    chunk_sums_kernel<<<NCH, 256, 0, stream>>>(cnt, chunk_sum);
    chunk_offsets_kernel<<<1, 64, 0, stream>>>(chunk_sum, chunk_off, row_ptr);
    scan_chunks_kernel<<<NCH, 256, 0, stream>>>(cnt, chunk_off, row_ptr, cursor);
    fill_csr_kernel<<<(N_EDGES + 255) / 256, 256, 0, stream>>>(edges, cursor, csr_src);
    invdeg_kernel<<<(N_NODES + 255) / 256, 256, 0, stream>>>(cnt, invdeg);
    graph_invcnt_kernel<<<1, 128, 0, stream>>>(batch, invcnt);

    // ---- 5 SAGE layers (bf16 h, MFMA gemm) ----
    const unsigned short* hcur = xb;
    unsigned short* bufs[2] = {hA, hB};
    for (int l = 0; l < 5; ++l) {
        agg_kernel<<<(N_NODES + 15) / 16, 256, 0, stream>>>(hcur, row_ptr, csr_src, invdeg, aggb);
        unsigned short* hnext = bufs[l & 1];
        sage_gemm_kernel<<<MPAD / 64, 256, 0, stream>>>(
            aggb, hcur, wcat + ((size_t)l << 15), bs[l], hnext);
        hcur = hnext;
    }

    // ---- pool + head ----
    pool_sum_kernel<<<POOL_GRID, 128, 0, stream>>>(hcur, batch, gsum);
    mlp_kernel<<<NGRAPH, 128, 0, stream>>>(gsum, invcnt, Wf1, bf1, Wf2, bf2, out);
}